// Round 3
// baseline (302.183 us; speedup 1.0000x reference)
//
#include <hip/hip_runtime.h>
#include <hip/hip_bf16.h>
#include <math.h>

#define B_   32
#define L_   512
#define C_   862
#define P_   720
#define H2_  1024
#define M_   (B_*C_)     // 27584 real rows
#define MP_  27648       // padded to multiple of 128
#define PP_  768         // P padded to multiple of 128

typedef __hip_bfloat16 bf16;
typedef __attribute__((ext_vector_type(8))) short s16x8;
typedef __attribute__((ext_vector_type(4))) float f32x4;

__device__ __forceinline__ void gload_lds16(const bf16* g, bf16* lds) {
    __builtin_amdgcn_global_load_lds(
        (const __attribute__((address_space(1))) void*)g,
        (__attribute__((address_space(3))) void*)lds, 16, 0, 0);
}

// ---------------------------------------------------------------- DCT matrix (bf16)
__global__ __launch_bounds__(256) void build_dct(bf16* __restrict__ D) {
    int idx = blockIdx.x * 256 + threadIdx.x;
    if (idx >= L_ * L_) return;
    int k = idx >> 9, l = idx & 511;
    double ang = M_PI * (double)((2 * l + 1) * k) / (2.0 * (double)L_);
    D[idx] = __float2bfloat16((float)(2.0 * cos(ang)));
}

// ------------------------------------------------------------- fp32 -> bf16 convert
__global__ __launch_bounds__(256) void cvt_bf16(const float* __restrict__ in,
                                                bf16* __restrict__ out, int n) {
    int i = blockIdx.x * 256 + threadIdx.x;
    if (i < n) out[i] = __float2bfloat16(in[i]);
}

// Wl (720,512) -> bf16 padded to (768,512) with zeros
__global__ __launch_bounds__(256) void cvt_wl_pad(const float* __restrict__ in,
                                                  bf16* __restrict__ out) {
    int i = blockIdx.x * 256 + threadIdx.x;
    if (i >= PP_ * L_) return;
    int r = i >> 9;
    out[i] = (r < P_) ? __float2bfloat16(in[i]) : __float2bfloat16(0.f);
}

// ---------------------------------------------------- x (B,L,C) -> Xc (B*C,L) bf16
__global__ __launch_bounds__(256) void transpose_x(const float* __restrict__ x,
                                                   bf16* __restrict__ Xc) {
    __shared__ float tile[32][33];
    int b  = blockIdx.z;
    int c0 = blockIdx.x * 32;
    int l0 = blockIdx.y * 32;
    int tx = threadIdx.x & 31, ty = threadIdx.x >> 5;   // 32 x 8
#pragma unroll
    for (int i = 0; i < 4; ++i) {
        int l = l0 + ty + i * 8, c = c0 + tx;
        float v = 0.f;
        if (l < L_ && c < C_) v = x[((size_t)b * L_ + l) * C_ + c];
        tile[ty + i * 8][tx] = v;
    }
    __syncthreads();
#pragma unroll
    for (int i = 0; i < 4; ++i) {
        int c = c0 + ty + i * 8, l = l0 + tx;
        if (c < C_ && l < L_)
            Xc[((size_t)b * C_ + c) * L_ + l] = __float2bfloat16(tile[tx][ty + i * 8]);
    }
}

// ------------------- row LayerNorm (512) fp32 in -> bf16 out; MUL: multiply by Xc
template <bool MUL>
__global__ __launch_bounds__(256) void layernorm_rows(const float* __restrict__ X,
                                                      const bf16* __restrict__ Xc,
                                                      const float* __restrict__ gamma,
                                                      const float* __restrict__ beta,
                                                      bf16* __restrict__ Out) {
    int row = blockIdx.x;
    const float* p = X + (size_t)row * L_;
    int tid = threadIdx.x;
    float v0 = p[tid], v1 = p[tid + 256];
    float s = v0 + v1, q = v0 * v0 + v1 * v1;
#pragma unroll
    for (int off = 32; off; off >>= 1) {
        s += __shfl_down(s, off);
        q += __shfl_down(q, off);
    }
    __shared__ float ss[4], sq[4];
    int wid = tid >> 6, lane = tid & 63;
    if (lane == 0) { ss[wid] = s; sq[wid] = q; }
    __syncthreads();
    if (tid == 0) {
        float S = ss[0] + ss[1] + ss[2] + ss[3];
        float Q = sq[0] + sq[1] + sq[2] + sq[3];
        float mu  = S * (1.f / L_);
        float var = Q * (1.f / L_) - mu * mu;
        ss[0] = mu;
        sq[0] = rsqrtf(var + 1e-6f);
    }
    __syncthreads();
    float mu = ss[0], r = sq[0];
    float y0 = (v0 - mu) * r * gamma[tid]       + beta[tid];
    float y1 = (v1 - mu) * r * gamma[tid + 256] + beta[tid + 256];
    if (MUL) {
        y0 *= __bfloat162float(Xc[(size_t)row * L_ + tid]);
        y1 *= __bfloat162float(Xc[(size_t)row * L_ + tid + 256]);
    }
    Out[(size_t)row * L_ + tid]       = __float2bfloat16(y0);
    Out[(size_t)row * L_ + tid + 256] = __float2bfloat16(y1);
}

// ------------------------------------------------------------- bf16 MFMA NT GEMM
// C[m,n] = act( A[m,:] . B[n,:] ) (+ bias[m] if BIAS_ROW)
// Tile 128x128, BK=32, 4 waves (2x2), 2-phase double-buffered pipeline:
//   issue next tile's global_load_lds BEFORE ds_read+MFMA of current tile,
//   single __syncthreads() (vmcnt(0)+barrier) per K-step at the END.
// M,N are PADDED multiples of 128; stores guarded by Mreal/Nreal.
// SCATTER_BC: n is flattened (b,c); store to out[b][m][c] (out is (B,P,C)).
template <int ACT, bool OUT_BF16, bool BIAS_ROW, bool SCATTER_BC>
__global__ __launch_bounds__(256, 2)
void gemm_bf16(const bf16* __restrict__ A, const bf16* __restrict__ Bm,
               const float* __restrict__ bias, void* __restrict__ Cout,
               int M, int N, int K, int Mreal, int Nreal) {
    constexpr int BK = 32;
    __shared__ bf16 As[2][128][BK];
    __shared__ bf16 Bs[2][128][BK];
    int tid  = threadIdx.x;
    int wave = tid >> 6, lane = tid & 63;
    int wr = wave >> 1, wc = wave & 1;            // 2x2 waves of 64x64
    size_t bm = (size_t)blockIdx.y * 128;
    size_t bn = (size_t)blockIdx.x * 128;

    f32x4 acc[4][4] = {};

    const bf16* Ab = A + bm * K;
    const bf16* Bb = Bm + bn * K;
    int srow = lane >> 2;            // 0..15
    int scol = (lane & 3) * 8;       // k elements
    int r0 = wave * 32;

    const int nt = K / BK;

    // prologue: stage tile 0 into buffer 0
    {
        gload_lds16(Ab + (size_t)(r0 + srow)      * K + scol, &As[0][r0][0]);
        gload_lds16(Ab + (size_t)(r0 + 16 + srow) * K + scol, &As[0][r0 + 16][0]);
        gload_lds16(Bb + (size_t)(r0 + srow)      * K + scol, &Bs[0][r0][0]);
        gload_lds16(Bb + (size_t)(r0 + 16 + srow) * K + scol, &Bs[0][r0 + 16][0]);
    }
    __syncthreads();

    int cur = 0;
    for (int t = 0; t < nt; ++t) {
        // issue NEXT tile's loads first (stay in flight during compute)
        if (t + 1 < nt) {
            int k0 = (t + 1) * BK;
            int nb = cur ^ 1;
            gload_lds16(Ab + (size_t)(r0 + srow)      * K + k0 + scol, &As[nb][r0][0]);
            gload_lds16(Ab + (size_t)(r0 + 16 + srow) * K + k0 + scol, &As[nb][r0 + 16][0]);
            gload_lds16(Bb + (size_t)(r0 + srow)      * K + k0 + scol, &Bs[nb][r0][0]);
            gload_lds16(Bb + (size_t)(r0 + 16 + srow) * K + k0 + scol, &Bs[nb][r0 + 16][0]);
        }

        int fr = lane & 15, kq = (lane >> 4) * 8;
        s16x8 af[4], bfv[4];
#pragma unroll
        for (int f = 0; f < 4; ++f) {
            af[f]  = *reinterpret_cast<const s16x8*>(&As[cur][wr * 64 + f * 16 + fr][kq]);
            bfv[f] = *reinterpret_cast<const s16x8*>(&Bs[cur][wc * 64 + f * 16 + fr][kq]);
        }
#pragma unroll
        for (int i = 0; i < 4; ++i)
#pragma unroll
            for (int j = 0; j < 4; ++j)
                acc[i][j] = __builtin_amdgcn_mfma_f32_16x16x32_bf16(af[i], bfv[j], acc[i][j], 0, 0, 0);

        __syncthreads();   // drains vmcnt(0): next buffer ready; all waves done reading cur
        cur ^= 1;
    }

    int fr = lane & 15, fq = lane >> 4;
#pragma unroll
    for (int j = 0; j < 4; ++j) {
        int n = (int)bn + wc * 64 + j * 16 + fr;
        if (n >= Nreal) continue;
        int sb = 0, sc = 0;
        if (SCATTER_BC) { sb = n / C_; sc = n - sb * C_; }
#pragma unroll
        for (int i = 0; i < 4; ++i) {
#pragma unroll
            for (int r = 0; r < 4; ++r) {
                int m = (int)bm + wr * 64 + i * 16 + fq * 4 + r;
                if (m >= Mreal) continue;
                float v = acc[i][j][r];
                if (BIAS_ROW) v += bias[m];
                if (ACT == 1) v = fmaxf(v, 0.f);
                if (ACT == 2) v = 1.f / (1.f + __expf(-v));
                if (SCATTER_BC) {
                    ((float*)Cout)[(size_t)sb * (P_ * C_) + (size_t)m * C_ + sc] = v;
                } else if (OUT_BF16) {
                    ((bf16*)Cout)[(size_t)m * N + n] = __float2bfloat16(v);
                } else {
                    ((float*)Cout)[(size_t)m * N + n] = v;
                }
            }
        }
    }
}

extern "C" void kernel_launch(void* const* d_in, const int* in_sizes, int n_in,
                              void* d_out, int out_size, void* d_ws, size_t ws_size,
                              hipStream_t stream) {
    const float* x     = (const float*)d_in[0];
    const float* W1    = (const float*)d_in[1];
    const float* W2    = (const float*)d_in[2];
    const float* gamma = (const float*)d_in[3];
    const float* beta  = (const float*)d_in[4];
    const float* Wl    = (const float*)d_in[5];
    const float* bl    = (const float*)d_in[6];
    float* out = (float*)d_out;

    char* ws = (char*)d_ws;
    bf16*  Xc   = (bf16*)ws;                                  // MP_*512 bf16
    bf16*  Fn   = Xc + (size_t)MP_ * L_;                      // MP_*512 bf16 (Fn, then Prod)
    bf16*  Hb   = Fn + (size_t)MP_ * L_;                      // MP_*1024 bf16
    float* Ff   = (float*)(Hb + (size_t)MP_ * H2_);           // MP_*512 f32 (freq, then fw)
    bf16*  Dbf  = (bf16*)(Ff + (size_t)MP_ * L_);             // 512*512
    bf16*  W1bf = Dbf + (size_t)L_ * L_;                      // 1024*512
    bf16*  W2bf = W1bf + (size_t)H2_ * L_;                    // 512*1024
    bf16*  Wlbf = W2bf + (size_t)L_ * H2_;                    // 768*512

    build_dct<<<(L_ * L_ + 255) / 256, 256, 0, stream>>>(Dbf);
    cvt_bf16<<<(H2_ * L_ + 255) / 256, 256, 0, stream>>>(W1, W1bf, H2_ * L_);
    cvt_bf16<<<(L_ * H2_ + 255) / 256, 256, 0, stream>>>(W2, W2bf, L_ * H2_);
    cvt_wl_pad<<<(PP_ * L_ + 255) / 256, 256, 0, stream>>>(Wl, Wlbf);
    transpose_x<<<dim3((C_ + 31) / 32, (L_ + 31) / 32, B_), 256, 0, stream>>>(x, Xc);

    // Stage A: freq = Xc . D^T   (f32 out)
    gemm_bf16<0, false, false, false><<<dim3(L_ / 128, MP_ / 128), 256, 0, stream>>>(
        Xc, Dbf, nullptr, Ff, MP_, L_, L_, M_, L_);
    layernorm_rows<false><<<M_, 256, 0, stream>>>(Ff, nullptr, gamma, beta, Fn);

    // Stage B: H = relu(Fn . W1^T)  (bf16 out)
    gemm_bf16<1, true, false, false><<<dim3(H2_ / 128, MP_ / 128), 256, 0, stream>>>(
        Fn, W1bf, nullptr, Hb, MP_, H2_, L_, M_, H2_);

    // Stage C: fw = sigmoid(H . W2^T)  (f32 out)
    gemm_bf16<2, false, false, false><<<dim3(L_ / 128, MP_ / 128), 256, 0, stream>>>(
        Hb, W2bf, nullptr, Ff, MP_, L_, H2_, M_, L_);
    // Prod = LN(fw) * Xc  (bf16, into Fn buffer)
    layernorm_rows<true><<<M_, 256, 0, stream>>>(Ff, Xc, gamma, beta, Fn);

    // Stage D: out[b,p,c] = Wl[p,:] . Prod[(b,c),:] + bl[p]  (operand-swapped, coalesced store)
    gemm_bf16<0, false, true, true><<<dim3(MP_ / 128, PP_ / 128), 256, 0, stream>>>(
        Wlbf, Fn, bl, out, PP_, MP_, L_, P_, M_);
}

// Round 4
// 266.294 us; speedup vs baseline: 1.1348x; 1.1348x over previous
//
#include <hip/hip_runtime.h>
#include <hip/hip_bf16.h>
#include <math.h>

#define B_   32
#define L_   512
#define C_   862
#define P_   720
#define H2_  1024
#define M_   (B_*C_)     // 27584 real rows
#define MP_  27648       // padded to multiple of 128
#define PP_  768         // P padded to multiple of 128

typedef __hip_bfloat16 bf16;
typedef __attribute__((ext_vector_type(8))) short s16x8;
typedef __attribute__((ext_vector_type(4))) float f32x4;

__device__ __forceinline__ void gload_lds16(const bf16* g, bf16* lds) {
    __builtin_amdgcn_global_load_lds(
        (const __attribute__((address_space(1))) void*)g,
        (__attribute__((address_space(3))) void*)lds, 16, 0, 0);
}

// ---------------------------------------------------------------- DCT matrix (bf16)
__global__ __launch_bounds__(256) void build_dct(bf16* __restrict__ D) {
    int idx = blockIdx.x * 256 + threadIdx.x;
    if (idx >= L_ * L_) return;
    int k = idx >> 9, l = idx & 511;
    double ang = M_PI * (double)((2 * l + 1) * k) / (2.0 * (double)L_);
    D[idx] = __float2bfloat16((float)(2.0 * cos(ang)));
}

// ------------------------------------------------------------- fp32 -> bf16 convert
__global__ __launch_bounds__(256) void cvt_bf16(const float* __restrict__ in,
                                                bf16* __restrict__ out, int n) {
    int i = blockIdx.x * 256 + threadIdx.x;
    if (i < n) out[i] = __float2bfloat16(in[i]);
}

// Wl (720,512) -> bf16 padded to (768,512) with zeros
__global__ __launch_bounds__(256) void cvt_wl_pad(const float* __restrict__ in,
                                                  bf16* __restrict__ out) {
    int i = blockIdx.x * 256 + threadIdx.x;
    if (i >= PP_ * L_) return;
    int r = i >> 9;
    out[i] = (r < P_) ? __float2bfloat16(in[i]) : __float2bfloat16(0.f);
}

// ---------------------------------------------------- x (B,L,C) -> Xc (B*C,L) bf16
__global__ __launch_bounds__(256) void transpose_x(const float* __restrict__ x,
                                                   bf16* __restrict__ Xc) {
    __shared__ float tile[32][33];
    int b  = blockIdx.z;
    int c0 = blockIdx.x * 32;
    int l0 = blockIdx.y * 32;
    int tx = threadIdx.x & 31, ty = threadIdx.x >> 5;   // 32 x 8
#pragma unroll
    for (int i = 0; i < 4; ++i) {
        int l = l0 + ty + i * 8, c = c0 + tx;
        float v = 0.f;
        if (l < L_ && c < C_) v = x[((size_t)b * L_ + l) * C_ + c];
        tile[ty + i * 8][tx] = v;
    }
    __syncthreads();
#pragma unroll
    for (int i = 0; i < 4; ++i) {
        int c = c0 + ty + i * 8, l = l0 + tx;
        if (c < C_ && l < L_)
            Xc[((size_t)b * C_ + c) * L_ + l] = __float2bfloat16(tile[tx][ty + i * 8]);
    }
}

// ------------------- row LayerNorm (512) fp32 in -> bf16 out; MUL: multiply by Xc
template <bool MUL>
__global__ __launch_bounds__(256) void layernorm_rows(const float* __restrict__ X,
                                                      const bf16* __restrict__ Xc,
                                                      const float* __restrict__ gamma,
                                                      const float* __restrict__ beta,
                                                      bf16* __restrict__ Out) {
    int row = blockIdx.x;
    const float* p = X + (size_t)row * L_;
    int tid = threadIdx.x;
    float v0 = p[tid], v1 = p[tid + 256];
    float s = v0 + v1, q = v0 * v0 + v1 * v1;
#pragma unroll
    for (int off = 32; off; off >>= 1) {
        s += __shfl_down(s, off);
        q += __shfl_down(q, off);
    }
    __shared__ float ss[4], sq[4];
    int wid = tid >> 6, lane = tid & 63;
    if (lane == 0) { ss[wid] = s; sq[wid] = q; }
    __syncthreads();
    if (tid == 0) {
        float S = ss[0] + ss[1] + ss[2] + ss[3];
        float Q = sq[0] + sq[1] + sq[2] + sq[3];
        float mu  = S * (1.f / L_);
        float var = Q * (1.f / L_) - mu * mu;
        ss[0] = mu;
        sq[0] = rsqrtf(var + 1e-6f);
    }
    __syncthreads();
    float mu = ss[0], r = sq[0];
    float y0 = (v0 - mu) * r * gamma[tid]       + beta[tid];
    float y1 = (v1 - mu) * r * gamma[tid + 256] + beta[tid + 256];
    if (MUL) {
        y0 *= __bfloat162float(Xc[(size_t)row * L_ + tid]);
        y1 *= __bfloat162float(Xc[(size_t)row * L_ + tid + 256]);
    }
    Out[(size_t)row * L_ + tid]       = __float2bfloat16(y0);
    Out[(size_t)row * L_ + tid + 256] = __float2bfloat16(y1);
}

// ------------------------------------------------------------- bf16 MFMA NT GEMM
// C[m,n] = act( A[m,:] . B[n,:] ) (+ bias[m] if BIAS_ROW)
// Tile 128x128, BK=64, 4 waves (2x2), single-buffered.
// LDS: [128][64] bf16 rows (128 B); reads XOR-swizzled (slot ^= row&7) to kill
// the 16-way column conflict; global_load_lds dest stays LINEAR, the global
// SOURCE is inverse-swizzled (rule #21: both-sides-or-neither).
// XCD-chunk blockIdx swizzle (T1): grids are all divisible by 8.
// M,N are PADDED multiples of 128; stores guarded by Mreal/Nreal.
// SCATTER_BC: n is flattened (b,c); store to out[b][m][c] (out is (B,P,C)).
template <int ACT, bool OUT_BF16, bool BIAS_ROW, bool SCATTER_BC>
__global__ __launch_bounds__(256, 2)
void gemm_bf16(const bf16* __restrict__ A, const bf16* __restrict__ Bm,
               const float* __restrict__ bias, void* __restrict__ Cout,
               int M, int N, int K, int Mreal, int Nreal) {
    constexpr int BK = 64;
    __shared__ bf16 As[128][BK];
    __shared__ bf16 Bs[128][BK];
    int tid  = threadIdx.x;
    int wave = tid >> 6, lane = tid & 63;
    int wr = wave >> 1, wc = wave & 1;            // 2x2 waves of 64x64

    // T1: XCD-aware chunked remap (nwg % 8 == 0 for every grid we launch)
    int nwg  = gridDim.x * gridDim.y;
    int b0   = blockIdx.y * gridDim.x + blockIdx.x;
    int qq   = nwg >> 3;
    int tile = (b0 & 7) * qq + (b0 >> 3);
    int bx   = tile % gridDim.x;
    int by   = tile / gridDim.x;
    size_t bm = (size_t)by * 128;
    size_t bn = (size_t)bx * 128;

    f32x4 acc[4][4] = {};

    const bf16* Ab = A + bm * K;
    const bf16* Bb = Bm + bn * K;

    // staging geometry: each instr covers 8 rows (128 B each) = 1 KiB
    int lrow  = lane >> 3;                 // 0..7 row within 8-row group
    int lslot = lane & 7;                  // 16B slot within row
    int srck  = (lslot ^ lrow) << 3;       // inverse-swizzled k element offset
    int r0 = wave * 32;                    // wave stages rows r0..r0+31 of A and B

    int fr = lane & 15, g = lane >> 4;
    const char* AsB = (const char*)&As[0][0];
    const char* BsB = (const char*)&Bs[0][0];

    for (int k0 = 0; k0 < K; k0 += BK) {
#pragma unroll
        for (int i = 0; i < 4; ++i) {
            gload_lds16(Ab + (size_t)(r0 + i * 8 + lrow) * K + k0 + srck, &As[r0 + i * 8][0]);
            gload_lds16(Bb + (size_t)(r0 + i * 8 + lrow) * K + k0 + srck, &Bs[r0 + i * 8][0]);
        }
        __syncthreads();   // vmcnt(0) drain + barrier: tile staged

#pragma unroll
        for (int t = 0; t < 2; ++t) {
            s16x8 af[4], bfv[4];
#pragma unroll
            for (int f = 0; f < 4; ++f) {
                int rowa = wr * 64 + f * 16 + fr;
                int rowb = wc * 64 + f * 16 + fr;
                int slot = ((t << 2) + g) ^ (fr & 7);   // row&7 == fr&7
                af[f]  = *reinterpret_cast<const s16x8*>(AsB + rowa * 128 + (slot << 4));
                bfv[f] = *reinterpret_cast<const s16x8*>(BsB + rowb * 128 + (slot << 4));
            }
#pragma unroll
            for (int i = 0; i < 4; ++i)
#pragma unroll
                for (int j = 0; j < 4; ++j)
                    acc[i][j] = __builtin_amdgcn_mfma_f32_16x16x32_bf16(af[i], bfv[j], acc[i][j], 0, 0, 0);
        }
        __syncthreads();   // all waves done reading before next stage overwrites
    }

    int fq = lane >> 4;
#pragma unroll
    for (int j = 0; j < 4; ++j) {
        int n = (int)bn + wc * 64 + j * 16 + fr;
        if (n >= Nreal) continue;
        int sb = 0, sc = 0;
        if (SCATTER_BC) { sb = n / C_; sc = n - sb * C_; }
#pragma unroll
        for (int i = 0; i < 4; ++i) {
#pragma unroll
            for (int r = 0; r < 4; ++r) {
                int m = (int)bm + wr * 64 + i * 16 + fq * 4 + r;
                if (m >= Mreal) continue;
                float v = acc[i][j][r];
                if (BIAS_ROW) v += bias[m];
                if (ACT == 1) v = fmaxf(v, 0.f);
                if (ACT == 2) v = 1.f / (1.f + __expf(-v));
                if (SCATTER_BC) {
                    ((float*)Cout)[(size_t)sb * (P_ * C_) + (size_t)m * C_ + sc] = v;
                } else if (OUT_BF16) {
                    ((bf16*)Cout)[(size_t)m * N + n] = __float2bfloat16(v);
                } else {
                    ((float*)Cout)[(size_t)m * N + n] = v;
                }
            }
        }
    }
}

extern "C" void kernel_launch(void* const* d_in, const int* in_sizes, int n_in,
                              void* d_out, int out_size, void* d_ws, size_t ws_size,
                              hipStream_t stream) {
    const float* x     = (const float*)d_in[0];
    const float* W1    = (const float*)d_in[1];
    const float* W2    = (const float*)d_in[2];
    const float* gamma = (const float*)d_in[3];
    const float* beta  = (const float*)d_in[4];
    const float* Wl    = (const float*)d_in[5];
    const float* bl    = (const float*)d_in[6];
    float* out = (float*)d_out;

    char* ws = (char*)d_ws;
    bf16*  Xc   = (bf16*)ws;                                  // MP_*512 bf16
    bf16*  Fn   = Xc + (size_t)MP_ * L_;                      // MP_*512 bf16 (Fn, then Prod)
    bf16*  Hb   = Fn + (size_t)MP_ * L_;                      // MP_*1024 bf16
    float* Ff   = (float*)(Hb + (size_t)MP_ * H2_);           // MP_*512 f32 (freq, then fw)
    bf16*  Dbf  = (bf16*)(Ff + (size_t)MP_ * L_);             // 512*512
    bf16*  W1bf = Dbf + (size_t)L_ * L_;                      // 1024*512
    bf16*  W2bf = W1bf + (size_t)H2_ * L_;                    // 512*1024
    bf16*  Wlbf = W2bf + (size_t)L_ * H2_;                    // 768*512

    build_dct<<<(L_ * L_ + 255) / 256, 256, 0, stream>>>(Dbf);
    cvt_bf16<<<(H2_ * L_ + 255) / 256, 256, 0, stream>>>(W1, W1bf, H2_ * L_);
    cvt_bf16<<<(L_ * H2_ + 255) / 256, 256, 0, stream>>>(W2, W2bf, L_ * H2_);
    cvt_wl_pad<<<(PP_ * L_ + 255) / 256, 256, 0, stream>>>(Wl, Wlbf);
    transpose_x<<<dim3((C_ + 31) / 32, (L_ + 31) / 32, B_), 256, 0, stream>>>(x, Xc);

    // Stage A: freq = Xc . D^T   (f32 out)   grid 4x216 = 864
    gemm_bf16<0, false, false, false><<<dim3(L_ / 128, MP_ / 128), 256, 0, stream>>>(
        Xc, Dbf, nullptr, Ff, MP_, L_, L_, M_, L_);
    layernorm_rows<false><<<M_, 256, 0, stream>>>(Ff, nullptr, gamma, beta, Fn);

    // Stage B: H = relu(Fn . W1^T)  (bf16 out)   grid 8x216 = 1728
    gemm_bf16<1, true, false, false><<<dim3(H2_ / 128, MP_ / 128), 256, 0, stream>>>(
        Fn, W1bf, nullptr, Hb, MP_, H2_, L_, M_, H2_);

    // Stage C: fw = sigmoid(H . W2^T)  (f32 out)   grid 4x216 = 864
    gemm_bf16<2, false, false, false><<<dim3(L_ / 128, MP_ / 128), 256, 0, stream>>>(
        Hb, W2bf, nullptr, Ff, MP_, L_, H2_, M_, L_);
    // Prod = LN(fw) * Xc  (bf16, into Fn buffer)
    layernorm_rows<true><<<M_, 256, 0, stream>>>(Ff, Xc, gamma, beta, Fn);

    // Stage D: out[b,p,c] = Wl[p,:] . Prod[(b,c),:] + bl[p]   grid 216x6 = 1296
    gemm_bf16<0, false, true, true><<<dim3(MP_ / 128, PP_ / 128), 256, 0, stream>>>(
        Wlbf, Fn, bl, out, PP_, MP_, L_, P_, M_);
}